// Round 9
// baseline (346.727 us; speedup 1.0000x reference)
//
#include <hip/hip_runtime.h>

// B=8, S=128, R=192, C=192. 7-point stencil on index-clamped field.
// Round-9: nt-hint A/B. Body/grid/block byte-identical to round-3 (best
// measured: 107.5 us) EXCEPT the three __builtin_nontemporal_* accesses are
// replaced by plain loads/stores. Rationale: five structurally different
// kernels (flat MLP, chained march, 384-thr, XCD-packed, LDS-staged) all
// plateau at 107-117 us with no pipe saturated; the nt hints are the one
// untested invariant. nt = no-allocate: the out stream (147 MB @ ~1.37 TB/s,
// flat across ALL variants) may be capped by the nt write path bypassing L2
// write-coalescing; the copy ubench that hits 6.3 TB/s uses plain stores.

#define BB 8
#define SS 128
#define RR 192
#define CC 192
#define PLANE (RR * CC)

typedef float v4f __attribute__((ext_vector_type(4)));

__device__ __forceinline__ v4f fix4(v4f c4, bool e0, bool e1)
{
    c4.x = e0 ? c4.y : c4.x;
    c4.w = e1 ? c4.z : c4.w;
    return c4;
}

__device__ __forceinline__ float stencil_pt(float pc, float pSm, float pSp,
                                            float pRm, float pRp,
                                            float pCm, float pCp, float d)
{
    const float inv2dx = 0.25f;        // 1/(2*2.0)
    const float inv2dy = 1.0f / 3.0f;  // 1/(2*1.5)
    const float inv2dz = 1.0f / 3.0f;
    const float invdx2 = 0.25f;        // 1/4.0
    const float invdy2 = 1.0f / 2.25f;
    const float invdz2 = 1.0f / 2.25f;

    float dcx = (pSp - pSm) * inv2dx;
    float dcy = (pRp - pRm) * inv2dy;
    float dcz = (pCp - pCm) * inv2dz;
    float F = dcx * dcx + dcy * dcy + dcz * dcz;
    float G = (pSp - 2.0f * pc + pSm) * invdx2
            + (pRp - 2.0f * pc + pRm) * invdy2
            + (pCp - 2.0f * pc + pCm) * invdz2;
    return -0.5f * F - d * G;
}

// block = (48, 4): tx covers C in float4 chunks, ty covers 4 rows.
// grid = (1, R/4, B*S/2): each thread emits outputs at i0 and i0+1.
__global__ __launch_bounds__(192) void flowp_kernel(
    const float* __restrict__ P,
    const float* __restrict__ D,
    float* __restrict__ out)
{
    const int tx = threadIdx.x;              // 0..47
    const int k0 = tx << 2;                  // 0..188
    const bool e0 = (tx == 0);
    const bool e1 = (tx == 47);
    const int kcm = e0 ? 1 : k0 - 1;         // clamped k0-1
    const int kcp = e1 ? CC - 2 : k0 + 4;    // clamped k0+4

    const int j  = blockIdx.y * 4 + threadIdx.y;  // 0..191
    const int bz = blockIdx.z;               // 0..511
    const int b  = bz >> 6;
    const int i0 = (bz & 63) << 1;           // 0,2,...,126
    const int i1 = i0 + 1;

    const int cj  = min(max(j,     1), RR - 2);
    const int cjm = min(max(j - 1, 1), RR - 2);
    const int cjp = min(max(j + 1, 1), RR - 2);

    // clamped plane indices for the 4 center rows (A=i0-1, B=i0, C=i0+1, Dp=i0+2)
    const int pA = min(max(i0 - 1, 1), SS - 2);
    const int pB = max(i0, 1);               // i0 <= 126 always
    const int pC = min(i1, SS - 2);
    const int pD = min(i0 + 2, SS - 2);

    const float* Pb  = P + b * (SS * PLANE);
    const float* rA  = Pb + pA * PLANE + cj  * CC;
    const float* rB  = Pb + pB * PLANE + cj  * CC;
    const float* rC  = Pb + pC * PLANE + cj  * CC;
    const float* rDp = Pb + pD * PLANE + cj  * CC;
    const float* rm0 = Pb + pB * PLANE + cjm * CC;
    const float* rp0 = Pb + pB * PLANE + cjp * CC;
    const float* rm1 = Pb + pC * PLANE + cjm * CC;
    const float* rp1 = Pb + pC * PLANE + cjp * CC;

    const int idx0 = ((b * SS + i0) * RR + j) * CC + k0;   // unclamped
    const int idx1 = idx0 + PLANE;

    // ---- issue ALL loads up-front (16 independent memory ops) ----
    v4f vA = *(const v4f*)(rA  + k0);
    v4f vB = *(const v4f*)(rB  + k0);
    v4f vC = *(const v4f*)(rC  + k0);
    v4f vDp = *(const v4f*)(rDp + k0);
    v4f m0 = *(const v4f*)(rm0 + k0);
    v4f p0 = *(const v4f*)(rp0 + k0);
    v4f m1 = *(const v4f*)(rm1 + k0);
    v4f p1 = *(const v4f*)(rp1 + k0);
    const float Bcm = rB[kcm];
    const float Bcp = rB[kcp];
    const float Ccm = rC[kcm];
    const float Ccp = rC[kcp];
    v4f d0 = *(const v4f*)(D + idx0);        // plain load (was nt)
    v4f d1 = *(const v4f*)(D + idx1);        // plain load (was nt)

    // ---- k-edge fixups ----
    vA = fix4(vA, e0, e1);
    vDp = fix4(vDp, e0, e1);
    m0 = fix4(m0, e0, e1);  p0 = fix4(p0, e0, e1);
    m1 = fix4(m1, e0, e1);  p1 = fix4(p1, e0, e1);

    const float Bw1 = e0 ? vB.y : vB.x;
    const float Bw2 = vB.y;
    const float Bw3 = vB.z;
    const float Bw4 = e1 ? vB.z : vB.w;
    const float Cw1 = e0 ? vC.y : vC.x;
    const float Cw2 = vC.y;
    const float Cw3 = vC.z;
    const float Cw4 = e1 ? vC.z : vC.w;

    // ---- output at i0: Sm = A, center = B-window, Sp = C-window ----
    v4f o0;
    o0.x = stencil_pt(Bw1, vA.x, Cw1, m0.x, p0.x, Bcm, Bw2, d0.x);
    o0.y = stencil_pt(Bw2, vA.y, Cw2, m0.y, p0.y, Bw1, Bw3, d0.y);
    o0.z = stencil_pt(Bw3, vA.z, Cw3, m0.z, p0.z, Bw2, Bw4, d0.z);
    o0.w = stencil_pt(Bw4, vA.w, Cw4, m0.w, p0.w, Bw3, Bcp, d0.w);
    *(v4f*)(out + idx0) = o0;                // plain store (was nt)

    // ---- output at i1: Sm = B-window, center = C-window, Sp = Dp ----
    v4f o1;
    o1.x = stencil_pt(Cw1, Bw1, vDp.x, m1.x, p1.x, Ccm, Cw2, d1.x);
    o1.y = stencil_pt(Cw2, Bw2, vDp.y, m1.y, p1.y, Cw1, Cw3, d1.y);
    o1.z = stencil_pt(Cw3, Bw3, vDp.z, m1.z, p1.z, Cw2, Cw4, d1.z);
    o1.w = stencil_pt(Cw4, Bw4, vDp.w, m1.w, p1.w, Cw3, Ccp, d1.w);
    *(v4f*)(out + idx1) = o1;                // plain store (was nt)
}

extern "C" void kernel_launch(void* const* d_in, const int* in_sizes, int n_in,
                              void* d_out, int out_size, void* d_ws, size_t ws_size,
                              hipStream_t stream) {
    const float* P = (const float*)d_in[1];
    const float* D = (const float*)d_in[2];
    float* out = (float*)d_out;

    dim3 block(48, 4, 1);                  // 192 threads = 3 waves
    dim3 grid(1, RR / 4, BB * SS / 2);     // 48 x 512 = 24576 blocks
    flowp_kernel<<<grid, block, 0, stream>>>(P, D, out);
}

// Round 11
// 337.391 us; speedup vs baseline: 1.0277x; 1.0277x over previous
//
#include <hip/hip_runtime.h>

// B=8, S=128, R=192, C=192. 7-point stencil on index-clamped field.
// Round-10: occupancy probe. Per-thread body, instruction mix, and nt policy
// byte-identical to round-3 (best: 107.5 us @ 78% occ, ~8 blocks/CU cap).
// Geometry only: 256-thread blocks (16x16 = 4 full waves) so the observed
// ~8-blocks/CU residency cap yields 32 waves/CU (100%) instead of 24 (75%).
// C axis splits into 3 k-panels of 64 floats (tx 0..15 x 4 floats); ty covers
// 16 j-rows. Tests the last untested axis: aggregate outstanding-request
// concurrency (+33% waves) against the 3.1 TB/s queuing plateau.

#define BB 8
#define SS 128
#define RR 192
#define CC 192
#define PLANE (RR * CC)

typedef float v4f __attribute__((ext_vector_type(4)));

__device__ __forceinline__ v4f fix4(v4f c4, bool e0, bool e1)
{
    c4.x = e0 ? c4.y : c4.x;
    c4.w = e1 ? c4.z : c4.w;
    return c4;
}

__device__ __forceinline__ float stencil_pt(float pc, float pSm, float pSp,
                                            float pRm, float pRp,
                                            float pCm, float pCp, float d)
{
    const float inv2dx = 0.25f;        // 1/(2*2.0)
    const float inv2dy = 1.0f / 3.0f;  // 1/(2*1.5)
    const float inv2dz = 1.0f / 3.0f;
    const float invdx2 = 0.25f;        // 1/4.0
    const float invdy2 = 1.0f / 2.25f;
    const float invdz2 = 1.0f / 2.25f;

    float dcx = (pSp - pSm) * inv2dx;
    float dcy = (pRp - pRm) * inv2dy;
    float dcz = (pCp - pCm) * inv2dz;
    float F = dcx * dcx + dcy * dcy + dcz * dcz;
    float G = (pSp - 2.0f * pc + pSm) * invdx2
            + (pRp - 2.0f * pc + pRm) * invdy2
            + (pCp - 2.0f * pc + pCm) * invdz2;
    return -0.5f * F - d * G;
}

// block = (16, 16): tx covers one 64-float k-panel in v4f chunks, ty covers
// 16 rows. grid = (3 panels, R/16, B*S/2). Two i-planes per thread (r3 body).
__global__ __launch_bounds__(256) void flowp_kernel(
    const float* __restrict__ P,
    const float* __restrict__ D,
    float* __restrict__ out)
{
    const int tx = threadIdx.x;              // 0..15
    const int ty = threadIdx.y;              // 0..15
    const int panel = blockIdx.x;            // 0..2
    const int k0 = (panel << 6) + (tx << 2); // 0..188
    const bool e0 = (panel == 0 && tx == 0);
    const bool e1 = (panel == 2 && tx == 15);
    const int kcm = e0 ? 1 : k0 - 1;         // clamped k0-1
    const int kcp = e1 ? CC - 2 : k0 + 4;    // clamped k0+4

    const int j  = blockIdx.y * 16 + ty;     // 0..191
    const int bz = blockIdx.z;               // 0..511
    const int b  = bz >> 6;
    const int i0 = (bz & 63) << 1;           // 0,2,...,126
    const int i1 = i0 + 1;

    const int cj  = min(max(j,     1), RR - 2);
    const int cjm = min(max(j - 1, 1), RR - 2);
    const int cjp = min(max(j + 1, 1), RR - 2);

    // clamped plane indices for the 4 center rows (A=i0-1, B=i0, C=i0+1, Dp=i0+2)
    const int pA = min(max(i0 - 1, 1), SS - 2);
    const int pB = max(i0, 1);               // i0 <= 126 always
    const int pC = min(i1, SS - 2);
    const int pD = min(i0 + 2, SS - 2);

    const float* Pb  = P + b * (SS * PLANE);
    const float* rA  = Pb + pA * PLANE + cj  * CC;
    const float* rB  = Pb + pB * PLANE + cj  * CC;
    const float* rC  = Pb + pC * PLANE + cj  * CC;
    const float* rDp = Pb + pD * PLANE + cj  * CC;
    const float* rm0 = Pb + pB * PLANE + cjm * CC;
    const float* rp0 = Pb + pB * PLANE + cjp * CC;
    const float* rm1 = Pb + pC * PLANE + cjm * CC;
    const float* rp1 = Pb + pC * PLANE + cjp * CC;

    const int idx0 = ((b * SS + i0) * RR + j) * CC + k0;   // unclamped
    const int idx1 = idx0 + PLANE;

    // ---- issue ALL loads up-front (16 independent memory ops) ----
    v4f vA = *(const v4f*)(rA  + k0);
    v4f vB = *(const v4f*)(rB  + k0);
    v4f vC = *(const v4f*)(rC  + k0);
    v4f vDp = *(const v4f*)(rDp + k0);
    v4f m0 = *(const v4f*)(rm0 + k0);
    v4f p0 = *(const v4f*)(rp0 + k0);
    v4f m1 = *(const v4f*)(rm1 + k0);
    v4f p1 = *(const v4f*)(rp1 + k0);
    const float Bcm = rB[kcm];
    const float Bcp = rB[kcp];
    const float Ccm = rC[kcm];
    const float Ccp = rC[kcp];
    v4f d0 = __builtin_nontemporal_load((const v4f*)(D + idx0));
    v4f d1 = __builtin_nontemporal_load((const v4f*)(D + idx1));

    // ---- k-edge fixups ----
    vA = fix4(vA, e0, e1);
    vDp = fix4(vDp, e0, e1);
    m0 = fix4(m0, e0, e1);  p0 = fix4(p0, e0, e1);
    m1 = fix4(m1, e0, e1);  p1 = fix4(p1, e0, e1);

    const float Bw1 = e0 ? vB.y : vB.x;
    const float Bw2 = vB.y;
    const float Bw3 = vB.z;
    const float Bw4 = e1 ? vB.z : vB.w;
    const float Cw1 = e0 ? vC.y : vC.x;
    const float Cw2 = vC.y;
    const float Cw3 = vC.z;
    const float Cw4 = e1 ? vC.z : vC.w;

    // ---- output at i0: Sm = A, center = B-window, Sp = C-window ----
    v4f o0;
    o0.x = stencil_pt(Bw1, vA.x, Cw1, m0.x, p0.x, Bcm, Bw2, d0.x);
    o0.y = stencil_pt(Bw2, vA.y, Cw2, m0.y, p0.y, Bw1, Bw3, d0.y);
    o0.z = stencil_pt(Bw3, vA.z, Cw3, m0.z, p0.z, Bw2, Bw4, d0.z);
    o0.w = stencil_pt(Bw4, vA.w, Cw4, m0.w, p0.w, Bw3, Bcp, d0.w);
    __builtin_nontemporal_store(o0, (v4f*)(out + idx0));

    // ---- output at i1: Sm = B-window, center = C-window, Sp = Dp ----
    v4f o1;
    o1.x = stencil_pt(Cw1, Bw1, vDp.x, m1.x, p1.x, Ccm, Cw2, d1.x);
    o1.y = stencil_pt(Cw2, Bw2, vDp.y, m1.y, p1.y, Cw1, Cw3, d1.y);
    o1.z = stencil_pt(Cw3, Bw3, vDp.z, m1.z, p1.z, Cw2, Cw4, d1.z);
    o1.w = stencil_pt(Cw4, Bw4, vDp.w, m1.w, p1.w, Cw3, Ccp, d1.w);
    __builtin_nontemporal_store(o1, (v4f*)(out + idx1));
}

extern "C" void kernel_launch(void* const* d_in, const int* in_sizes, int n_in,
                              void* d_out, int out_size, void* d_ws, size_t ws_size,
                              hipStream_t stream) {
    const float* P = (const float*)d_in[1];
    const float* D = (const float*)d_in[2];
    float* out = (float*)d_out;

    dim3 block(16, 16, 1);                 // 256 threads = 4 full waves
    dim3 grid(3, RR / 16, BB * SS / 2);    // 3 x 12 x 512 = 18432 blocks
    flowp_kernel<<<grid, block, 0, stream>>>(P, D, out);
}